// Round 1
// baseline (140.164 us; speedup 1.0000x reference)
//
#include <hip/hip_runtime.h>
#include <stdint.h>

#define XC 4096      // CB*BS
#define MT 256       // batch rows per workgroup
#define MAXNNZ 13

typedef __attribute__((ext_vector_type(8))) short short8;
typedef __attribute__((ext_vector_type(4))) float f32x4;

static __device__ __forceinline__ unsigned short f2bf(float f) {
    union { float f; unsigned int u; } c; c.f = f;
    unsigned int u = c.u;
    unsigned int r = 0x7FFFu + ((u >> 16) & 1u);
    return (unsigned short)((u + r) >> 16);
}

// w_bf16[n][o][s] = bf16(mask * weight), packed 4 elems/thread
__global__ void prep_w(const float* __restrict__ w, const float* __restrict__ m,
                       unsigned short* __restrict__ out, int nf4) {
    int i = blockIdx.x * 256 + threadIdx.x;
    if (i >= nf4) return;
    const float4* w4 = (const float4*)w;
    const float4* m4 = (const float4*)m;
    float4 a = w4[i], b = m4[i];
    unsigned int lo = (unsigned int)f2bf(a.x * b.x) | ((unsigned int)f2bf(a.y * b.y) << 16);
    unsigned int hi = (unsigned int)f2bf(a.z * b.z) | ((unsigned int)f2bf(a.w * b.w) << 16);
    ((uint2*)out)[i] = make_uint2(lo, hi);
}

// One workgroup = (row block r, batch tile of 256 rows). 4 waves, 64 rows/wave.
// Y[b, r*32+o] = sum_n sum_s x[b, col[n]*32+s] * w[n,o,s] + bias[r*32+o]
__global__ __launch_bounds__(256, 3) void bsl_mfma(
    const float* __restrict__ x, const int* __restrict__ crow,
    const int* __restrict__ cols, const unsigned short* __restrict__ wbf,
    const float* __restrict__ wf, const float* __restrict__ mf,
    const float* __restrict__ bias, float* __restrict__ out, int use_ws)
{
    // +8 pad per 32-short row: rows stay 16B-aligned, b128 reads ~conflict-free
    __shared__ unsigned short w_lds[MAXNNZ][32][40];  // 33,280 B
    __shared__ unsigned short x_lds[MT][40];          // 20,480 B

    const int tid = threadIdx.x;
    const int bx  = blockIdx.x;
    const int r   = bx & 127;        // row block (consecutive blocks share batch tile -> L2)
    const int mt  = bx >> 7;
    const int row0 = mt * MT;
    const int start = crow[r];
    const int nnzr  = crow[r + 1] - start;

    // ---- stage masked bf16 weights for this row block into LDS ----
    if (use_ws) {
        const uint4* src = (const uint4*)(wbf + (size_t)start * 1024);
        for (int i = tid; i < nnzr * 128; i += 256) {
            int nn = i >> 7, rem = i & 127;
            int o = rem >> 2, sg = rem & 3;
            uint4 v = src[i];
            *(uint4*)&w_lds[nn][o][sg * 8] = v;
        }
    } else {
        // fallback: convert fp32 weight*mask inline (no workspace needed)
        const float4* wsrc = (const float4*)(wf + (size_t)start * 1024);
        const float4* msrc = (const float4*)(mf + (size_t)start * 1024);
        for (int i = tid; i < nnzr * 256; i += 256) {
            int nn = i >> 8, rem = i & 255;
            int o = rem >> 3, sg = rem & 7;
            float4 a = wsrc[i], b = msrc[i];
            unsigned int lo = (unsigned int)f2bf(a.x * b.x) | ((unsigned int)f2bf(a.y * b.y) << 16);
            unsigned int hi = (unsigned int)f2bf(a.z * b.z) | ((unsigned int)f2bf(a.w * b.w) << 16);
            *(uint2*)&w_lds[nn][o][sg * 4] = make_uint2(lo, hi);
        }
    }

    const int lane = tid & 63;
    const int wv   = tid >> 6;
    const int l15  = lane & 15;
    const int quad = lane >> 4;

    f32x4 acc[4][2];
    #pragma unroll
    for (int i = 0; i < 4; ++i)
        #pragma unroll
        for (int j = 0; j < 2; ++j)
            acc[i][j] = (f32x4){0.f, 0.f, 0.f, 0.f};

    // x staging: thread loads 8 float4 (rows rr+32j, 16B segment s4)
    const int s4 = tid & 7;
    const int rr = tid >> 3;
    float4 v[8];
    {
        int c = cols[start];
        const float* xb = x + (size_t)(row0 + rr) * XC + c * 32 + s4 * 4;
        #pragma unroll
        for (int j = 0; j < 8; ++j)
            v[j] = *(const float4*)(xb + (size_t)j * 32 * XC);
    }

    for (int nn = 0; nn < nnzr; ++nn) {
        __syncthreads();   // prior-iter LDS reads done (iter 0: also covers nothing harmful)
        #pragma unroll
        for (int j = 0; j < 8; ++j) {
            unsigned int lo = (unsigned int)f2bf(v[j].x) | ((unsigned int)f2bf(v[j].y) << 16);
            unsigned int hi = (unsigned int)f2bf(v[j].z) | ((unsigned int)f2bf(v[j].w) << 16);
            *(uint2*)&x_lds[rr + j * 32][s4 * 4] = make_uint2(lo, hi);
        }
        __syncthreads();   // x chunk (and on iter 0, w) visible to all

        // prefetch next chunk's x while MFMAs run
        if (nn + 1 < nnzr) {
            int c = cols[start + nn + 1];
            const float* xb = x + (size_t)(row0 + rr) * XC + c * 32 + s4 * 4;
            #pragma unroll
            for (int j = 0; j < 8; ++j)
                v[j] = *(const float4*)(xb + (size_t)j * 32 * XC);
        }

        // B frags: lane holds w[o = l15(+16)][k = quad*8 + j]
        short8 b0 = *(const short8*)&w_lds[nn][l15][quad * 8];
        short8 b1 = *(const short8*)&w_lds[nn][16 + l15][quad * 8];
        #pragma unroll
        for (int mi = 0; mi < 4; ++mi) {
            // A frag: lane holds x[m = l15][k = quad*8 + j]
            short8 a = *(const short8*)&x_lds[wv * 64 + mi * 16 + l15][quad * 8];
            acc[mi][0] = __builtin_amdgcn_mfma_f32_16x16x32_bf16(a, b0, acc[mi][0], 0, 0, 0);
            acc[mi][1] = __builtin_amdgcn_mfma_f32_16x16x32_bf16(a, b1, acc[mi][1], 0, 0, 0);
        }
    }

    // epilogue: C/D layout col = l15 (=o), row = quad*4 + reg (=m)
    float b0v = bias[r * 32 + l15];
    float b1v = bias[r * 32 + 16 + l15];
    #pragma unroll
    for (int mi = 0; mi < 4; ++mi) {
        int rbase = row0 + wv * 64 + mi * 16 + quad * 4;
        #pragma unroll
        for (int reg = 0; reg < 4; ++reg) {
            float* op = out + (size_t)(rbase + reg) * XC + r * 32;
            op[l15]      = acc[mi][0][reg] + b0v;
            op[16 + l15] = acc[mi][1][reg] + b1v;
        }
    }
}

extern "C" void kernel_launch(void* const* d_in, const int* in_sizes, int n_in,
                              void* d_out, int out_size, void* d_ws, size_t ws_size,
                              hipStream_t stream) {
    const float* x      = (const float*)d_in[0];
    const int*   crow   = (const int*)d_in[1];
    const int*   cols   = (const int*)d_in[2];
    const float* mask   = (const float*)d_in[3];
    const float* weight = (const float*)d_in[4];
    const float* bias   = (const float*)d_in[5];
    float* out = (float*)d_out;

    const int wel   = in_sizes[4];        // nnz * 32 * 32 = 1,703,936
    const int rb    = in_sizes[1] - 1;    // 128
    const int batch = in_sizes[0] / XC;   // 2048

    const size_t wbytes = (size_t)wel * 2;
    int use_ws = (ws_size >= wbytes) ? 1 : 0;
    unsigned short* wbf = (unsigned short*)d_ws;

    if (use_ws) {
        int nf4 = wel / 4;
        prep_w<<<dim3((nf4 + 255) / 256), dim3(256), 0, stream>>>(weight, mask, wbf, nf4);
    }
    int grid = rb * (batch / MT);         // 128 * 8 = 1024
    bsl_mfma<<<dim3(grid), dim3(256), 0, stream>>>(x, crow, cols, wbf, weight, mask,
                                                   bias, out, use_ws);
}

// Round 2
// 125.799 us; speedup vs baseline: 1.1142x; 1.1142x over previous
//
#include <hip/hip_runtime.h>
#include <stdint.h>

#define XC 4096      // CB*BS
#define MT 256       // batch rows per workgroup (main path)
#define NNZ 13       // nnz blocks per row block (setup guarantees)

typedef __attribute__((ext_vector_type(8))) short short8;
typedef __attribute__((ext_vector_type(4))) float f32x4;

static __device__ __forceinline__ unsigned short f2bf(float f) {
    union { float f; unsigned int u; } c; c.f = f;
    unsigned int u = c.u;
    unsigned int r = 0x7FFFu + ((u >> 16) & 1u);
    return (unsigned short)((u + r) >> 16);
}
static __device__ __forceinline__ unsigned int pk2(float a, float b) {
    return (unsigned int)f2bf(a) | ((unsigned int)f2bf(b) << 16);
}

// async global->LDS, 16B per lane; LDS dest = uniform base + lane*16
#define GLD_LDS16(g, l) __builtin_amdgcn_global_load_lds(                      \
    (const __attribute__((address_space(1))) void*)(g),                        \
    (__attribute__((address_space(3))) void*)(l), 16, 0, 0)

// ---- prep: x fp32 -> bf16, w*mask fp32 -> bf16 (fused, one launch) ----
__global__ void prep(const float* __restrict__ x, const float* __restrict__ w,
                     const float* __restrict__ m, unsigned short* __restrict__ xbf,
                     unsigned short* __restrict__ wbf, int nx4, int nw4) {
    int i = blockIdx.x * 256 + threadIdx.x;
    if (i < nx4) {
        float4 a = ((const float4*)x)[i];
        ((uint2*)xbf)[i] = make_uint2(pk2(a.x, a.y), pk2(a.z, a.w));
    } else {
        int k = i - nx4;
        if (k < nw4) {
            float4 a = ((const float4*)w)[k];
            float4 b = ((const float4*)m)[k];
            ((uint2*)wbf)[k] = make_uint2(pk2(a.x * b.x, a.y * b.y),
                                          pk2(a.z * b.z, a.w * b.w));
        }
    }
}

// ---- main: barrier-free wave-private pipeline ----
// grid = 128 r-blocks * 8 batch tiles; 4 waves; wave owns 64 batch rows.
// w frags in VGPRs; x chunks triple-buffered in wave-private LDS via
// global_load_lds; sync = s_waitcnt vmcnt(N) only.
__global__ __launch_bounds__(256, 2) void bsl_mfma2(
    const unsigned short* __restrict__ xbf, const int* __restrict__ cols,
    const unsigned short* __restrict__ wbf, const float* __restrict__ bias,
    float* __restrict__ out)
{
    // 4 waves * 3 bufs * (64 rows * 32 shorts) = 48 KiB, XOR-swizzled
    __shared__ __align__(16) unsigned short x_lds[4 * 3 * 2048];

    const int tid  = threadIdx.x;
    const int bx   = blockIdx.x;
    const int r    = bx & 127;    // consecutive blocks share batch tile -> L2/L3
    const int mt   = bx >> 7;
    const int row0 = mt * MT;
    const int start = r * NNZ;

    const int lane = tid & 63;
    const int wv   = tid >> 6;
    const int l15  = lane & 15;
    const int quad = lane >> 4;

    int cseq[NNZ];
    #pragma unroll
    for (int nn = 0; nn < NNZ; ++nn) cseq[nn] = cols[start + nn];

    // B frags: lane holds w[o = l15 (+16)][k = quad*8 + j]; coalesced 16B loads
    short8 wfrag[NNZ][2];
    {
        const unsigned short* wp0 = wbf + (size_t)start * 1024 + l15 * 32 + quad * 8;
        #pragma unroll
        for (int nn = 0; nn < NNZ; ++nn) {
            wfrag[nn][0] = *(const short8*)(wp0 + nn * 1024);
            wfrag[nn][1] = *(const short8*)(wp0 + nn * 1024 + 512);
        }
    }

    // staging geometry: lane covers row (j*16 + lane>>2), 16B unit
    // q = (lane&3) ^ ((lane>>3)&3)  (XOR swizzle; dest = base + lane*16)
    const int row0w = row0 + wv * 64;
    const int rl    = lane >> 2;
    const int qsw   = (lane & 3) ^ ((lane >> 3) & 3);
    const unsigned short* xsrc = xbf + ((size_t)row0w + rl) * XC + qsw * 8;
    unsigned short* lbase = &x_lds[wv * 6144];

    #pragma unroll
    for (int p = 0; p < 3; ++p) {   // issue chunks 0..2
        const unsigned short* g = xsrc + cseq[p] * 32;
        #pragma unroll
        for (int j = 0; j < 4; ++j)
            GLD_LDS16(g + (size_t)j * 16 * XC, lbase + p * 2048 + j * 512);
    }

    f32x4 acc[4][2];
    #pragma unroll
    for (int i = 0; i < 4; ++i)
        #pragma unroll
        for (int j = 0; j < 2; ++j)
            acc[i][j] = (f32x4){0.f, 0.f, 0.f, 0.f};

    const int sw = (l15 >> 1) & 3;   // read-side swizzle term

    #pragma unroll
    for (int nn = 0; nn < NNZ; ++nn) {
        // chunk nn complete when only the 2 newest chunks remain outstanding
        if (nn < NNZ - 2)       asm volatile("s_waitcnt vmcnt(8)" ::: "memory");
        else if (nn == NNZ - 2) asm volatile("s_waitcnt vmcnt(4)" ::: "memory");
        else                    asm volatile("s_waitcnt vmcnt(0)" ::: "memory");

        const unsigned short* xb = lbase + (nn % 3) * 2048;
        #pragma unroll
        for (int mi = 0; mi < 4; ++mi) {
            const int rloc = mi * 16 + l15;
            short8 a = *(const short8*)&xb[rloc * 32 + ((quad ^ sw) * 8)];
            acc[mi][0] = __builtin_amdgcn_mfma_f32_16x16x32_bf16(a, wfrag[nn][0], acc[mi][0], 0, 0, 0);
            acc[mi][1] = __builtin_amdgcn_mfma_f32_16x16x32_bf16(a, wfrag[nn][1], acc[mi][1], 0, 0, 0);
        }
        // issue chunk nn+3 AFTER MFMAs: their lgkm waits guarantee the
        // slot's ds_reads (in-order LDS) completed -> no WAR hazard
        if (nn + 3 < NNZ) {
            const int p = nn + 3;
            const unsigned short* g = xsrc + cseq[p] * 32;
            #pragma unroll
            for (int j = 0; j < 4; ++j)
                GLD_LDS16(g + (size_t)j * 16 * XC, lbase + (p % 3) * 2048 + j * 512);
        }
    }

    // epilogue: C/D layout col=l15(=o), row=quad*4+reg(=m)
    const float b0v = bias[r * 32 + l15];
    const float b1v = bias[r * 32 + 16 + l15];
    #pragma unroll
    for (int mi = 0; mi < 4; ++mi) {
        const int rbase = row0 + wv * 64 + mi * 16 + quad * 4;
        #pragma unroll
        for (int reg = 0; reg < 4; ++reg) {
            float* op = out + (size_t)(rbase + reg) * XC + r * 32;
            op[l15]      = acc[mi][0][reg] + b0v;
            op[16 + l15] = acc[mi][1][reg] + b1v;
        }
    }
}

// ---- fallback (ws too small / unexpected shape): round-1 kernel, inline conv ----
__global__ __launch_bounds__(256, 3) void bsl_fallback(
    const float* __restrict__ x, const int* __restrict__ crow,
    const int* __restrict__ cols, const float* __restrict__ wf,
    const float* __restrict__ mf, const float* __restrict__ bias,
    float* __restrict__ out)
{
    __shared__ unsigned short w_lds[NNZ][32][40];
    __shared__ unsigned short x_lds[MT][40];

    const int tid = threadIdx.x;
    const int bx  = blockIdx.x;
    const int r   = bx & 127;
    const int mt  = bx >> 7;
    const int row0 = mt * MT;
    const int start = crow[r];
    const int nnzr  = crow[r + 1] - start;

    const float4* wsrc = (const float4*)(wf + (size_t)start * 1024);
    const float4* msrc = (const float4*)(mf + (size_t)start * 1024);
    for (int i = tid; i < nnzr * 256; i += 256) {
        int nn = i >> 8, rem = i & 255;
        int o = rem >> 3, sg = rem & 7;
        float4 a = wsrc[i], b = msrc[i];
        *(uint2*)&w_lds[nn][o][sg * 4] =
            make_uint2(pk2(a.x * b.x, a.y * b.y), pk2(a.z * b.z, a.w * b.w));
    }

    const int lane = tid & 63;
    const int wv   = tid >> 6;
    const int l15  = lane & 15;
    const int quad = lane >> 4;

    f32x4 acc[4][2];
    #pragma unroll
    for (int i = 0; i < 4; ++i)
        #pragma unroll
        for (int j = 0; j < 2; ++j)
            acc[i][j] = (f32x4){0.f, 0.f, 0.f, 0.f};

    const int s4 = tid & 7;
    const int rr = tid >> 3;
    float4 v[8];
    {
        int c = cols[start];
        const float* xb = x + (size_t)(row0 + rr) * XC + c * 32 + s4 * 4;
        #pragma unroll
        for (int j = 0; j < 8; ++j) v[j] = *(const float4*)(xb + (size_t)j * 32 * XC);
    }

    for (int nn = 0; nn < nnzr; ++nn) {
        __syncthreads();
        #pragma unroll
        for (int j = 0; j < 8; ++j)
            *(uint2*)&x_lds[rr + j * 32][s4 * 4] =
                make_uint2(pk2(v[j].x, v[j].y), pk2(v[j].z, v[j].w));
        __syncthreads();

        if (nn + 1 < nnzr) {
            int c = cols[start + nn + 1];
            const float* xb = x + (size_t)(row0 + rr) * XC + c * 32 + s4 * 4;
            #pragma unroll
            for (int j = 0; j < 8; ++j) v[j] = *(const float4*)(xb + (size_t)j * 32 * XC);
        }

        short8 b0 = *(const short8*)&w_lds[nn][l15][quad * 8];
        short8 b1 = *(const short8*)&w_lds[nn][16 + l15][quad * 8];
        #pragma unroll
        for (int mi = 0; mi < 4; ++mi) {
            short8 a = *(const short8*)&x_lds[wv * 64 + mi * 16 + l15][quad * 8];
            acc[mi][0] = __builtin_amdgcn_mfma_f32_16x16x32_bf16(a, b0, acc[mi][0], 0, 0, 0);
            acc[mi][1] = __builtin_amdgcn_mfma_f32_16x16x32_bf16(a, b1, acc[mi][1], 0, 0, 0);
        }
    }

    const float b0v = bias[r * 32 + l15];
    const float b1v = bias[r * 32 + 16 + l15];
    #pragma unroll
    for (int mi = 0; mi < 4; ++mi) {
        const int rbase = row0 + wv * 64 + mi * 16 + quad * 4;
        #pragma unroll
        for (int reg = 0; reg < 4; ++reg) {
            float* op = out + (size_t)(rbase + reg) * XC + r * 32;
            op[l15]      = acc[mi][0][reg] + b0v;
            op[16 + l15] = acc[mi][1][reg] + b1v;
        }
    }
}

extern "C" void kernel_launch(void* const* d_in, const int* in_sizes, int n_in,
                              void* d_out, int out_size, void* d_ws, size_t ws_size,
                              hipStream_t stream) {
    const float* x      = (const float*)d_in[0];
    const int*   crow   = (const int*)d_in[1];
    const int*   cols   = (const int*)d_in[2];
    const float* mask   = (const float*)d_in[3];
    const float* weight = (const float*)d_in[4];
    const float* bias   = (const float*)d_in[5];
    float* out = (float*)d_out;

    const int xel   = in_sizes[0];        // 2048*4096
    const int wel   = in_sizes[4];        // 1664*1024
    const int rb    = in_sizes[1] - 1;    // 128
    const int batch = xel / XC;           // 2048

    const size_t xb_bytes = (size_t)xel * 2;
    const size_t wb_bytes = (size_t)wel * 2;

    const bool fast = (ws_size >= xb_bytes + wb_bytes) && (rb == 128) &&
                      (in_sizes[2] == rb * NNZ) && (batch % MT == 0);

    if (fast) {
        unsigned short* xbf = (unsigned short*)d_ws;
        unsigned short* wbf = (unsigned short*)((char*)d_ws + xb_bytes);
        int nx4 = xel / 4, nw4 = wel / 4;
        int tot = nx4 + nw4;
        prep<<<dim3((tot + 255) / 256), dim3(256), 0, stream>>>(x, weight, mask,
                                                                xbf, wbf, nx4, nw4);
        bsl_mfma2<<<dim3(rb * (batch / MT)), dim3(256), 0, stream>>>(xbf, cols, wbf,
                                                                     bias, out);
    } else {
        bsl_fallback<<<dim3(rb * (batch / MT)), dim3(256), 0, stream>>>(
            x, crow, cols, weight, mask, bias, out);
    }
}